// Round 3
// baseline (2599.062 us; speedup 1.0000x reference)
//
#include <hip/hip_runtime.h>
#include <math.h>

#define N_ROWS 65536
#define CB 1024

// ---------------------------------------------------------------------------
// Exact emulation of numpy's pairwise_sum for n=64 fp32 (AVX-512 path):
// lane sums (x[l]+x[l+16])+(x[l+32]+x[l+48]), then reduce tree at distance
// 8,4,2,1. fp contract OFF so squares are not fused into adds.
// VERIFIED absmax=0 (R1, R2).
// ---------------------------------------------------------------------------
__device__ __forceinline__ float tree_sum64_sq(const float* x) {
#pragma clang fp contract(off)
    float sq[64];
#pragma unroll
    for (int i = 0; i < 64; ++i) sq[i] = x[i] * x[i];
    float s[16];
#pragma unroll
    for (int l = 0; l < 16; ++l) s[l] = (sq[l] + sq[l + 16]) + (sq[l + 32] + sq[l + 48]);
    float t[8];
#pragma unroll
    for (int l = 0; l < 8; ++l) t[l] = s[l] + s[l + 8];
    float u[4];
#pragma unroll
    for (int l = 0; l < 4; ++l) u[l] = t[l] + t[l + 4];
    float v0 = u[0] + u[2];
    float v1 = u[1] + u[3];
    return v0 + v1;
}

// sorted-triple insert, strict < (ties keep earlier-inserted = lower index;
// ascending-j feed preserves lax.top_k tie-breaking).  VERIFIED (R1, R2).
__device__ __forceinline__ void top3_insert(float d, int j,
                                            float& v0, float& v1, float& v2,
                                            int& i0, int& i1, int& i2) {
    bool b0 = d < v0, b1 = d < v1, b2 = d < v2;
    v2 = b1 ? v1 : (b2 ? d : v2);
    i2 = b1 ? i1 : (b2 ? j : i2);
    v1 = b0 ? v0 : (b1 ? d : v1);
    i1 = b0 ? i0 : (b1 ? j : i1);
    v0 = b0 ? d : v0;
    i0 = b0 ? j : i0;
}

// B[j] = np.sum(emb[j]**2)  (exact tree emulation)
__global__ __launch_bounds__(256) void embB_kernel(const float* __restrict__ emb,
                                                   float* __restrict__ B) {
    int j = blockIdx.x * 256 + threadIdx.x;
    if (j >= CB) return;
    float e[64];
    const float4* e4 = (const float4*)(emb + (size_t)j * 64);
#pragma unroll
    for (int k = 0; k < 16; ++k) {
        float4 v = e4[k];
        e[4 * k] = v.x; e[4 * k + 1] = v.y; e[4 * k + 2] = v.z; e[4 * k + 3] = v.w;
    }
    B[j] = tree_sum64_sq(e);
}

// ---------------------------------------------------------------------------
// Fused scoring + encodings fill, occupancy-fixed (R2 post-mortem):
//   grid 1024 blocks (4 blocks/CU = 4 waves/SIMD at VGPR~116) x 256 threads.
//   Block owns 64 rows; each row owned by a quad of lanes, lane (t&3)=split s
//   scans j in [256s, 256s+256). Quad partials merged via __shfl in ascending
//   split order (== R1's verified merge semantics). Zero-fill of this block's
//   own 64-row encodings slice is interleaved into the j-loop (overlaps HBM
//   writes with VALU FMAs); __syncthreads() drains vmcnt(0) before the ones.
// Exact per-j math unchanged from verified R1/R2: ascending-k single-acc fmaf
// chain, d = (A+Bj) - 2*acc.
// ---------------------------------------------------------------------------
__global__ __launch_bounds__(256) void mega_kernel(const float* __restrict__ z,
                                                   const float* __restrict__ emb,
                                                   const float* __restrict__ B,
                                                   float* __restrict__ out0,
                                                   float* __restrict__ out3,
                                                   float* __restrict__ out4,
                                                   int* __restrict__ hist,
                                                   float* __restrict__ lossAcc) {
    const int t = threadIdx.x;
    const int s = t & 3;                       // split (j-range quarter)
    const int r = t >> 2;                      // row within block [0,64)
    const int row = blockIdx.x * 64 + r;

    // full 64-dim z row in registers (quad-mates load same row; L1 broadcast)
    float zr[64];
    const float4* z4 = (const float4*)(z + (size_t)row * 64);
#pragma unroll
    for (int k = 0; k < 16; ++k) {
        float4 v = z4[k];
        zr[4 * k] = v.x; zr[4 * k + 1] = v.y; zr[4 * k + 2] = v.z; zr[4 * k + 3] = v.w;
    }
    float A = tree_sum64_sq(zr);

    // this block's encodings slice: its own 64 rows * 3072 floats = 49152 f4
    float4* zb = (float4*)out3 + (size_t)blockIdx.x * 49152;
    const float4 zero4 = make_float4(0.0f, 0.0f, 0.0f, 0.0f);

    float v0 = 3.402823466e38f, v1 = 3.402823466e38f, v2 = 3.402823466e38f;
    int i0 = 0, i1 = 0, i2 = 0;
    const int jbase = s * 256;

    for (int g = 0; g < 64; ++g) {
        // interleaved zero-fill: 3 coalesced float4 stores per 4-j group
        zb[(size_t)(3 * g + 0) * 256 + t] = zero4;
        zb[(size_t)(3 * g + 1) * 256 + t] = zero4;
        zb[(size_t)(3 * g + 2) * 256 + t] = zero4;

#pragma unroll
        for (int u = 0; u < 4; u += 2) {       // 2 independent FMA chains
            const int j0 = jbase + 4 * g + u;
            const int j1 = j0 + 1;
            const float4* e0p = (const float4*)(emb + (size_t)j0 * 64);
            const float4* e1p = (const float4*)(emb + (size_t)j1 * 64);
            float b0v = B[j0], b1v = B[j1];
            float a0 = 0.0f, a1 = 0.0f;
#pragma unroll
            for (int k = 0; k < 16; ++k) {
                float4 e0 = e0p[k], e1 = e1p[k];
                float x0 = zr[4 * k], x1 = zr[4 * k + 1];
                float x2 = zr[4 * k + 2], x3 = zr[4 * k + 3];
                a0 = fmaf(x0, e0.x, a0); a0 = fmaf(x1, e0.y, a0);
                a0 = fmaf(x2, e0.z, a0); a0 = fmaf(x3, e0.w, a0);
                a1 = fmaf(x0, e1.x, a1); a1 = fmaf(x1, e1.y, a1);
                a1 = fmaf(x2, e1.z, a1); a1 = fmaf(x3, e1.w, a1);
            }
            float d0 = (A + b0v) - 2.0f * a0;  // 2*acc exact -> contraction-safe
            float d1 = (A + b1v) - 2.0f * a1;
            top3_insert(d0, j0, v0, v1, v2, i0, i1, i2);
            top3_insert(d1, j1, v0, v1, v2, i0, i1, i2);
        }
    }

    // intra-quad merge via shuffles, ascending split order (== verified R1
    // merge: lower split's equal-distance entry wins)
    const int lanebase = (t & 63) & ~3;
    float w0 = v0, w1 = v1, w2 = v2;
    int q0 = i0, q1 = i1, q2 = i2;
#pragma unroll
    for (int ss = 1; ss < 4; ++ss) {
        float u0 = __shfl(v0, lanebase + ss);
        float u1 = __shfl(v1, lanebase + ss);
        float u2 = __shfl(v2, lanebase + ss);
        int   p0 = __shfl(i0, lanebase + ss);
        int   p1 = __shfl(i1, lanebase + ss);
        int   p2 = __shfl(i2, lanebase + ss);
        top3_insert(u0, p0, w0, w1, w2, q0, q1, q2);
        top3_insert(u1, p1, w0, w1, w2, q0, q1, q2);
        top3_insert(u2, p2, w0, w1, w2, q0, q1, q2);
    }
    // broadcast merged indices to the whole quad
    const int b0i = __shfl(q0, lanebase);
    const int b1i = __shfl(q1, lanebase);
    const int b2i = __shfl(q2, lanebase);

    // barrier drains vmcnt(0): this block's zero-fill (covering exactly this
    // block's rows) completes before any one-writes. Block-local hazard only.
    __syncthreads();

    if (s == 0) {
        size_t rb = (size_t)row * 3072;
        out3[rb + b0i]        = 1.0f;
        out3[rb + 1024 + b1i] = 1.0f;
        out3[rb + 2048 + b2i] = 1.0f;
        size_t ob = (size_t)row * 3;
        out4[ob]     = (float)b0i;
        out4[ob + 1] = (float)b1i;
        out4[ob + 2] = (float)b2i;
        atomicAdd(&hist[b0i], 1);
        atomicAdd(&hist[b1i], 1);
        atomicAdd(&hist[b2i], 1);
    }

    // epilogue, quad-distributed: lane s handles dims [16s, 16s+16)
    const float* e0 = emb + (size_t)b0i * 64 + 16 * s;
    const float* e1 = emb + (size_t)b1i * 64 + 16 * s;
    const float* e2 = emb + (size_t)b2i * 64 + 16 * s;
    float4* o4 = (float4*)(out0 + (size_t)row * 64 + 16 * s);

    float lsum = 0.0f;
#pragma unroll
    for (int c = 0; c < 4; ++c) {
        float4 st;
        {
            int l = 4 * c;
            float zq = ((e0[l] + e1[l]) + e2[l]) / 3.0f;
            float df = zq - zr[16 * s + l];
            st.x = zr[16 * s + l] + df;
            lsum = fmaf(df, df, lsum);
        }
        {
            int l = 4 * c + 1;
            float zq = ((e0[l] + e1[l]) + e2[l]) / 3.0f;
            float df = zq - zr[16 * s + l];
            st.y = zr[16 * s + l] + df;
            lsum = fmaf(df, df, lsum);
        }
        {
            int l = 4 * c + 2;
            float zq = ((e0[l] + e1[l]) + e2[l]) / 3.0f;
            float df = zq - zr[16 * s + l];
            st.z = zr[16 * s + l] + df;
            lsum = fmaf(df, df, lsum);
        }
        {
            int l = 4 * c + 3;
            float zq = ((e0[l] + e1[l]) + e2[l]) / 3.0f;
            float df = zq - zr[16 * s + l];
            st.w = zr[16 * s + l] + df;
            lsum = fmaf(df, df, lsum);
        }
        o4[c] = st;
    }

    // wave-level reduce of loss partial, one atomic per wave
#pragma unroll
    for (int off = 32; off >= 1; off >>= 1) lsum += __shfl_down(lsum, off);
    if ((t & 63) == 0) atomicAdd(lossAcc, lsum);
}

// Perplexity from histogram + loss finalize.
__global__ __launch_bounds__(256) void finalize_kernel(const int* __restrict__ hist,
                                                       const float* __restrict__ lossAcc,
                                                       float* __restrict__ out1,
                                                       float* __restrict__ out2) {
    __shared__ float red[256];
    int t = threadIdx.x;
    float local = 0.0f;
    for (int b = t; b < CB; b += 256) {
        float em = (float)hist[b] / 196608.0f;
        local += em * logf(em + 1e-10f);
    }
    red[t] = local;
    __syncthreads();
    for (int s = 128; s >= 1; s >>= 1) {
        if (t < s) red[t] += red[t + s];
        __syncthreads();
    }
    if (t == 0) {
        *out2 = expf(-red[0]);
        float m = *lossAcc / 4194304.0f;
        *out1 = 0.25f * m + m;   // BETA_C*mse + mse (stop_gradient = id fwd)
    }
}

extern "C" void kernel_launch(void* const* d_in, const int* in_sizes, int n_in,
                              void* d_out, int out_size, void* d_ws, size_t ws_size,
                              hipStream_t stream) {
    const float* z   = (const float*)d_in[0];   // [16,64,64,64] -> 65536 x 64
    const float* emb = (const float*)d_in[1];   // [1024, 64]

    float* out  = (float*)d_out;
    float* out0 = out;                                    // z_q_st     4194304
    float* out1 = out + 4194304;                          // loss       1
    float* out2 = out + 4194305;                          // perplexity 1
    float* out3 = out + 4194306;                          // encodings  201326592
    float* out4 = out + 4194306 + 201326592ll;            // topk_idx   196608

    int*   hist    = (int*)d_ws;                          // 1024 ints @ 0
    float* lossAcc = (float*)((char*)d_ws + 4096);        // 1 float
    float* B       = (float*)((char*)d_ws + 8192);        // 1024 floats

    hipMemsetAsync(d_ws, 0, 4096 + 16, stream);           // hist + lossAcc

    embB_kernel<<<4, 256, 0, stream>>>(emb, B);
    mega_kernel<<<N_ROWS / 64, 256, 0, stream>>>(z, emb, B, out0, out3, out4,
                                                 hist, lossAcc);
    finalize_kernel<<<1, 256, 0, stream>>>(hist, lossAcc, out1, out2);
}

// Round 4
// 1181.772 us; speedup vs baseline: 2.1993x; 2.1993x over previous
//
#include <hip/hip_runtime.h>
#include <math.h>

#define N_ROWS 65536
#define CB 1024
#define SPLITS 4
#define JS (CB / SPLITS)   // 256 codebook entries per split

// ---------------------------------------------------------------------------
// Exact emulation of numpy's pairwise_sum for n=64 fp32 (AVX-512 path).
// fp contract OFF so squares are not fused into adds. VERIFIED absmax=0
// (R1, R2, R3).
// ---------------------------------------------------------------------------
__device__ __forceinline__ float tree_sum64_sq(const float* x) {
#pragma clang fp contract(off)
    float sq[64];
#pragma unroll
    for (int i = 0; i < 64; ++i) sq[i] = x[i] * x[i];
    float s[16];
#pragma unroll
    for (int l = 0; l < 16; ++l) s[l] = (sq[l] + sq[l + 16]) + (sq[l + 32] + sq[l + 48]);
    float t[8];
#pragma unroll
    for (int l = 0; l < 8; ++l) t[l] = s[l] + s[l + 8];
    float u[4];
#pragma unroll
    for (int l = 0; l < 4; ++l) u[l] = t[l] + t[l + 4];
    float v0 = u[0] + u[2];
    float v1 = u[1] + u[3];
    return v0 + v1;
}

// sorted-triple insert, strict < (ties keep earlier-inserted = lower index;
// ascending-j feed preserves lax.top_k tie-breaking). VERIFIED (R1-R3).
__device__ __forceinline__ void top3_insert(float d, int j,
                                            float& v0, float& v1, float& v2,
                                            int& i0, int& i1, int& i2) {
    bool b0 = d < v0, b1 = d < v1, b2 = d < v2;
    v2 = b1 ? v1 : (b2 ? d : v2);
    i2 = b1 ? i1 : (b2 ? j : i2);
    v1 = b0 ? v0 : (b1 ? d : v1);
    i1 = b0 ? i0 : (b1 ? j : i1);
    v0 = b0 ? d : v0;
    i0 = b0 ? j : i0;
}

// B[j] = np.sum(emb[j]**2)  (exact tree emulation)
__global__ __launch_bounds__(256) void embB_kernel(const float* __restrict__ emb,
                                                   float* __restrict__ B) {
    int j = blockIdx.x * 256 + threadIdx.x;
    if (j >= CB) return;
    float e[64];
    const float4* e4 = (const float4*)(emb + (size_t)j * 64);
#pragma unroll
    for (int k = 0; k < 16; ++k) {
        float4 v = e4[k];
        e[4 * k] = v.x; e[4 * k + 1] = v.y; e[4 * k + 2] = v.z; e[4 * k + 3] = v.w;
    }
    B[j] = tree_sum64_sq(e);
}

// ---------------------------------------------------------------------------
// R1's verified score structure (j split by blockIdx -> wave-uniform j ->
// scalar emb loads; 1024 blocks = 4 blocks/CU = 4 waves/SIMD) + fused
// encodings zero-fill: block (rowBlk, split) zero-fills the split-th quarter
// of rowBlk's 256-row encodings slice, interleaved 3 float4-stores per 4-j
// group (fire-and-forget; drains at HBM rate while VALU does FMAs).
// zeros->ones ordering is guaranteed by the kernel boundary (merge_kernel
// writes the ones). Exact per-j math unchanged: ascending-k single-acc fmaf
// chain, d = (A+Bj) - 2*acc (2*acc exact -> contraction-safe).
// ---------------------------------------------------------------------------
__global__ __launch_bounds__(256) void score_fused_kernel(const float* __restrict__ z,
                                                          const float* __restrict__ emb,
                                                          const float* __restrict__ B,
                                                          float* __restrict__ out3,
                                                          float* __restrict__ scrD,
                                                          int* __restrict__ scrI) {
    const int bid = blockIdx.x;
    const int split = bid & (SPLITS - 1);
    const int rowBlk = bid >> 2;
    const int t = threadIdx.x;
    const int row = rowBlk * 256 + t;

    float zr[64];
    const float4* z4 = (const float4*)(z + (size_t)row * 64);
#pragma unroll
    for (int k = 0; k < 16; ++k) {
        float4 v = z4[k];
        zr[4 * k] = v.x; zr[4 * k + 1] = v.y; zr[4 * k + 2] = v.z; zr[4 * k + 3] = v.w;
    }
    float A = tree_sum64_sq(zr);

    // this block's zero-fill region: quarter of rowBlk's encodings slice
    // (256 rows * 3072 floats = 196608 float4; quarter = 49152 = 192/thread)
    float4* zb = (float4*)out3 + (size_t)rowBlk * 196608 + (size_t)split * 49152;
    const float4 zero4 = make_float4(0.0f, 0.0f, 0.0f, 0.0f);

    float v0 = 3.402823466e38f, v1 = 3.402823466e38f, v2 = 3.402823466e38f;
    int i0 = 0, i1 = 0, i2 = 0;
    const int jbase = split * JS;

    for (int g = 0; g < 64; ++g) {
        // interleaved zero-fill: 3 coalesced float4 stores per 4-j group
        zb[(size_t)(3 * g + 0) * 256 + t] = zero4;
        zb[(size_t)(3 * g + 1) * 256 + t] = zero4;
        zb[(size_t)(3 * g + 2) * 256 + t] = zero4;

#pragma unroll
        for (int u = 0; u < 4; u += 2) {       // 2 independent FMA chains
            const int j0 = jbase + 4 * g + u;  // wave-uniform
            const int j1 = j0 + 1;
            const float4* e0p = (const float4*)(emb + (size_t)j0 * 64);
            const float4* e1p = (const float4*)(emb + (size_t)j1 * 64);
            float b0v = B[j0], b1v = B[j1];    // uniform -> scalar loads
            float a0 = 0.0f, a1 = 0.0f;
#pragma unroll
            for (int k = 0; k < 16; ++k) {
                float4 e0 = e0p[k], e1 = e1p[k];   // uniform -> scalar loads
                float x0 = zr[4 * k], x1 = zr[4 * k + 1];
                float x2 = zr[4 * k + 2], x3 = zr[4 * k + 3];
                a0 = fmaf(x0, e0.x, a0); a0 = fmaf(x1, e0.y, a0);
                a0 = fmaf(x2, e0.z, a0); a0 = fmaf(x3, e0.w, a0);
                a1 = fmaf(x0, e1.x, a1); a1 = fmaf(x1, e1.y, a1);
                a1 = fmaf(x2, e1.z, a1); a1 = fmaf(x3, e1.w, a1);
            }
            float d0 = (A + b0v) - 2.0f * a0;
            float d1 = (A + b1v) - 2.0f * a1;
            top3_insert(d0, j0, v0, v1, v2, i0, i1, i2);
            top3_insert(d1, j1, v0, v1, v2, i0, i1, i2);
        }
    }

    size_t o = ((size_t)split * N_ROWS + row) * 3;
    scrD[o] = v0; scrD[o + 1] = v1; scrD[o + 2] = v2;
    scrI[o] = i0; scrI[o + 1] = i1; scrI[o + 2] = i2;
}

// ---------------------------------------------------------------------------
// Merge 4 split-partials (ascending split order == verified tie semantics),
// then per-row epilogue: one-hot ones (zeros already laid down by score),
// topk_idx, z_q_st, hist, loss. VERIFIED math (R1).
// ---------------------------------------------------------------------------
__global__ __launch_bounds__(256) void merge_kernel(const float* __restrict__ z,
                                                    const float* __restrict__ emb,
                                                    const float* __restrict__ scrD,
                                                    const int* __restrict__ scrI,
                                                    float* __restrict__ out0,
                                                    float* __restrict__ out3,
                                                    float* __restrict__ out4,
                                                    int* __restrict__ hist,
                                                    float* __restrict__ lossAcc) {
    int row = blockIdx.x * 256 + threadIdx.x;

    float v0 = 3.402823466e38f, v1 = 3.402823466e38f, v2 = 3.402823466e38f;
    int i0 = 0, i1 = 0, i2 = 0;
#pragma unroll
    for (int s = 0; s < SPLITS; ++s) {
        size_t o = ((size_t)s * N_ROWS + row) * 3;
#pragma unroll
        for (int t = 0; t < 3; ++t) {
            float d = scrD[o + t];
            int j = scrI[o + t];
            top3_insert(d, j, v0, v1, v2, i0, i1, i2);
        }
    }

    // one-hot ones (zeros written by score_fused; ordered by kernel boundary)
    size_t rb = (size_t)row * 3072;
    out3[rb + i0]        = 1.0f;
    out3[rb + 1024 + i1] = 1.0f;
    out3[rb + 2048 + i2] = 1.0f;

    const float* e0 = emb + (size_t)i0 * 64;
    const float* e1 = emb + (size_t)i1 * 64;
    const float* e2 = emb + (size_t)i2 * 64;
    const float4* z4 = (const float4*)(z + (size_t)row * 64);
    float4* o4 = (float4*)(out0 + (size_t)row * 64);

    float lsum = 0.0f;
#pragma unroll
    for (int k4 = 0; k4 < 16; ++k4) {
        float4 zv = z4[k4];
        float4 st;
        {
            int k = 4 * k4;
            float zq = ((e0[k] + e1[k]) + e2[k]) / 3.0f;
            float df = zq - zv.x;
            st.x = zv.x + df;
            lsum = fmaf(df, df, lsum);
        }
        {
            int k = 4 * k4 + 1;
            float zq = ((e0[k] + e1[k]) + e2[k]) / 3.0f;
            float df = zq - zv.y;
            st.y = zv.y + df;
            lsum = fmaf(df, df, lsum);
        }
        {
            int k = 4 * k4 + 2;
            float zq = ((e0[k] + e1[k]) + e2[k]) / 3.0f;
            float df = zq - zv.z;
            st.z = zv.z + df;
            lsum = fmaf(df, df, lsum);
        }
        {
            int k = 4 * k4 + 3;
            float zq = ((e0[k] + e1[k]) + e2[k]) / 3.0f;
            float df = zq - zv.w;
            st.w = zv.w + df;
            lsum = fmaf(df, df, lsum);
        }
        o4[k4] = st;
    }

    size_t ob = (size_t)row * 3;
    out4[ob]     = (float)i0;
    out4[ob + 1] = (float)i1;
    out4[ob + 2] = (float)i2;
    atomicAdd(&hist[i0], 1);
    atomicAdd(&hist[i1], 1);
    atomicAdd(&hist[i2], 1);

#pragma unroll
    for (int off = 32; off >= 1; off >>= 1) lsum += __shfl_down(lsum, off);
    if ((threadIdx.x & 63) == 0) atomicAdd(lossAcc, lsum);
}

// Perplexity from histogram + loss finalize.
__global__ __launch_bounds__(256) void finalize_kernel(const int* __restrict__ hist,
                                                       const float* __restrict__ lossAcc,
                                                       float* __restrict__ out1,
                                                       float* __restrict__ out2) {
    __shared__ float red[256];
    int t = threadIdx.x;
    float local = 0.0f;
    for (int b = t; b < CB; b += 256) {
        float em = (float)hist[b] / 196608.0f;
        local += em * logf(em + 1e-10f);
    }
    red[t] = local;
    __syncthreads();
    for (int s = 128; s >= 1; s >>= 1) {
        if (t < s) red[t] += red[t + s];
        __syncthreads();
    }
    if (t == 0) {
        *out2 = expf(-red[0]);
        float m = *lossAcc / 4194304.0f;
        *out1 = 0.25f * m + m;   // BETA_C*mse + mse (stop_gradient = id fwd)
    }
}

extern "C" void kernel_launch(void* const* d_in, const int* in_sizes, int n_in,
                              void* d_out, int out_size, void* d_ws, size_t ws_size,
                              hipStream_t stream) {
    const float* z   = (const float*)d_in[0];   // [16,64,64,64] -> 65536 x 64
    const float* emb = (const float*)d_in[1];   // [1024, 64]

    float* out  = (float*)d_out;
    float* out0 = out;                                    // z_q_st     4194304
    float* out1 = out + 4194304;                          // loss       1
    float* out2 = out + 4194305;                          // perplexity 1
    float* out3 = out + 4194306;                          // encodings  201326592
    float* out4 = out + 4194306 + 201326592ll;            // topk_idx   196608

    int*   hist    = (int*)d_ws;                          // 1024 ints @ 0
    float* lossAcc = (float*)((char*)d_ws + 4096);        // 1 float
    float* B       = (float*)((char*)d_ws + 8192);        // 1024 floats
    // split-partial scratch in ws (out3 is concurrently zero-filled now):
    float* scrD = (float*)((char*)d_ws + 16384);          // 4*65536*3 floats
    int*   scrI = (int*)((char*)d_ws + 16384 + (size_t)SPLITS * N_ROWS * 3 * 4);

    hipMemsetAsync(d_ws, 0, 4096 + 16, stream);           // hist + lossAcc

    embB_kernel<<<4, 256, 0, stream>>>(emb, B);
    score_fused_kernel<<<(N_ROWS / 256) * SPLITS, 256, 0, stream>>>(z, emb, B,
                                                                    out3, scrD, scrI);
    merge_kernel<<<N_ROWS / 256, 256, 0, stream>>>(z, emb, scrD, scrI,
                                                   out0, out3, out4, hist, lossAcc);
    finalize_kernel<<<1, 256, 0, stream>>>(hist, lossAcc, out1, out2);
}